// Round 8
// baseline (524.922 us; speedup 1.0000x reference)
//
#include <hip/hip_runtime.h>
#include <hip/hip_bf16.h>

typedef __attribute__((ext_vector_type(8))) short bf16x8;
typedef __attribute__((ext_vector_type(4))) float f32x4;

#define NB 2048      // batch
#define ND 1280      // per-stream dim
#define NK 5120      // 4*ND
#define NE 512       // EMBED

static __device__ inline unsigned short f2bf(float x) {
    union { float f; unsigned u; } c; c.f = x;
    unsigned r = c.u + 0x7FFFu + ((c.u >> 16) & 1u);
    return (unsigned short)(r >> 16);
}

// ---------------------------------------------------------------------------
// Kernel 1: fused masked-mean over T for all 4 segments -> feat bf16 [B][4D]
// Thread owns ADJACENT float4-chunks (2c, 2c+1): a wave reads one contiguous
// 2 KB span per t-plane (and writes one contiguous 2 KB feat span).
// Dispatch order (tail-packing): fixed-len segs (1,3) first, masked (0,2),
// W1-transpose blocks last. blocks [0,5120): reduce; [5120,7680): W1T.
// ---------------------------------------------------------------------------
__global__ __launch_bounds__(256) void reduce_w1t_kernel(
    const f32x4* __restrict__ q, const f32x4* __restrict__ vq,
    const f32x4* __restrict__ aa, const f32x4* __restrict__ va,
    const int* __restrict__ qlen, const int* __restrict__ alen,
    ushort4* __restrict__ feat,
    const float* __restrict__ W1, unsigned short* __restrict__ w1t,
    float* __restrict__ s1s2)
{
    __shared__ unsigned short lds[32][33];

    if (blockIdx.x >= 5120) {
        // ---- W1 transpose path ----
        const int bid = blockIdx.x - 5120;
        if (bid == 0) {
            ((f32x4*)s1s2)[threadIdx.x] = (f32x4){0.f, 0.f, 0.f, 0.f};
        }
        const int kb = (bid >> 4) * 32;
        const int nb = (bid & 15) * 32;
        const int tx = threadIdx.x & 31;
        const int ty = threadIdx.x >> 5;   // 0..7
        #pragma unroll
        for (int i = 0; i < 4; ++i) {
            int k = kb + ty + i * 8;
            lds[ty + i * 8][tx] = f2bf(W1[(long)k * NE + nb + tx]);
        }
        __syncthreads();
        #pragma unroll
        for (int i = 0; i < 4; ++i) {
            int n = nb + ty + i * 8;
            w1t[(long)n * NK + kb + tx] = lds[tx][ty + i * 8];
        }
        return;
    }

    // ---- masked-mean path (seg order: 1,3,0,2) ----
    const int sb = blockIdx.x / 1280;
    const int rem = blockIdx.x - sb * 1280;
    const int seg = (sb == 0) ? 1 : (sb == 1) ? 3 : (sb == 2) ? 0 : 2;

    const int r = rem * 256 + threadIdx.x;
    const int b = r / 160;
    const int c = r - b * 160;                  // pair index 0..159

    const long base = (long)b * 320 + 2 * c;    // float4 units, adjacent pair
    const long stride = (long)NB * 320;         // one t-plane

    f32x4 a0 = {0.f, 0.f, 0.f, 0.f};
    f32x4 a1 = {0.f, 0.f, 0.f, 0.f};
    float inv;

    if (seg == 1 || seg == 3) {
        const f32x4* src = (seg == 1) ? vq : va;
        #pragma unroll 8
        for (int t = 0; t < 64; ++t) {
            f32x4 v0 = __builtin_nontemporal_load(&src[base + (long)t * stride]);
            f32x4 v1 = __builtin_nontemporal_load(&src[base + 1 + (long)t * stride]);
            a0 += v0;
            a1 += v1;
        }
        inv = 1.0f / 64.0f;
    } else {
        const f32x4* src = (seg == 0) ? q : aa;
        const int len = (seg == 0) ? qlen[b] : alen[b];
        #pragma unroll 8
        for (int t = 0; t < len; ++t) {
            f32x4 v0 = __builtin_nontemporal_load(&src[base + (long)t * stride]);
            f32x4 v1 = __builtin_nontemporal_load(&src[base + 1 + (long)t * stride]);
            a0 += v0;
            a1 += v1;
        }
        inv = 1.0f / (float)len;
    }

    ushort4 o0, o1;
    o0.x = f2bf(a0.x * inv); o0.y = f2bf(a0.y * inv);
    o0.z = f2bf(a0.z * inv); o0.w = f2bf(a0.w * inv);
    o1.x = f2bf(a1.x * inv); o1.y = f2bf(a1.y * inv);
    o1.z = f2bf(a1.z * inv); o1.w = f2bf(a1.w * inv);
    const long fb = (long)b * (NK / 4) + seg * 320 + 2 * c;
    feat[fb] = o0;
    feat[fb + 1] = o1;
}

// ---------------------------------------------------------------------------
// Kernel 2: bf16 MFMA GEMM, tiles 64x64, wave=32x32 (acc[2][2]), K=5120,
// grid 256 blocks (1/CU), XCD-aware mapping (m = bid&31).
// LDS double-buffer + prefetch depth 2 (two named reg sets, statically
// unrolled x2); one barrier per sub-step. Fused bias/ELU/store/BN epilogue.
// ---------------------------------------------------------------------------
__global__ __launch_bounds__(256) void gemm_kernel(
    const unsigned short* __restrict__ feat, const unsigned short* __restrict__ w1t,
    const float* __restrict__ b1,
    float* __restrict__ h, float* __restrict__ s1s2)
{
    __shared__ int4 As[2][64 * 9];   // 2 x 64 rows x 144B (16B pad)
    __shared__ int4 Bs[2][64 * 9];

    const int bid = blockIdx.x;
    const int m0 = (bid & 31) << 6;         // m-tile fastest -> same-m on same XCD
    const int n0 = (bid >> 5) << 6;         // 0..448

    const int t = threadIdx.x;
    const int l = t & 63;
    const int w = t >> 6;
    const int wm = (w >> 1) << 5;           // 0 or 32
    const int wn = (w & 1) << 5;            // 0 or 32
    const int srow = t >> 2;                // 0..63
    const int sc = (t & 3) << 1;            // 16B-chunk 0,2,4,6

    const unsigned short* Ab = feat + (long)(m0 + srow) * NK + sc * 8;
    const unsigned short* Bb = w1t + (long)(n0 + srow) * NK + sc * 8;

    f32x4 acc[2][2] = {};

    // prefetch set 0 (k-step k0) and set 1 (k-step k0+64)
    int4 pa0_0 = *(const int4*)(Ab);
    int4 pa1_0 = *(const int4*)(Ab + 8);
    int4 pb0_0 = *(const int4*)(Bb);
    int4 pb1_0 = *(const int4*)(Bb + 8);
    int4 pa0_1 = *(const int4*)(Ab + 64);
    int4 pa1_1 = *(const int4*)(Ab + 72);
    int4 pb0_1 = *(const int4*)(Bb + 64);
    int4 pb1_1 = *(const int4*)(Bb + 72);

    #pragma unroll 1
    for (int k0 = 0; k0 < NK; k0 += 128) {
        // ---------- even sub-step: set0 -> buffer 0 ----------
        As[0][srow * 9 + sc] = pa0_0;
        As[0][srow * 9 + sc + 1] = pa1_0;
        Bs[0][srow * 9 + sc] = pb0_0;
        Bs[0][srow * 9 + sc + 1] = pb1_0;
        if (k0 + 128 < NK) {
            pa0_0 = *(const int4*)(Ab + k0 + 128);
            pa1_0 = *(const int4*)(Ab + k0 + 136);
            pb0_0 = *(const int4*)(Bb + k0 + 128);
            pb1_0 = *(const int4*)(Bb + k0 + 136);
        }
        __syncthreads();
        #pragma unroll
        for (int kk = 0; kk < 2; ++kk) {
            const int kc = kk * 4 + (l >> 4);
            bf16x8 af0 = *(const bf16x8*)&As[0][(wm + (l & 15)) * 9 + kc];
            bf16x8 af1 = *(const bf16x8*)&As[0][(wm + 16 + (l & 15)) * 9 + kc];
            bf16x8 bf0 = *(const bf16x8*)&Bs[0][(wn + (l & 15)) * 9 + kc];
            bf16x8 bf1 = *(const bf16x8*)&Bs[0][(wn + 16 + (l & 15)) * 9 + kc];
            acc[0][0] = __builtin_amdgcn_mfma_f32_16x16x32_bf16(af0, bf0, acc[0][0], 0, 0, 0);
            acc[0][1] = __builtin_amdgcn_mfma_f32_16x16x32_bf16(af0, bf1, acc[0][1], 0, 0, 0);
            acc[1][0] = __builtin_amdgcn_mfma_f32_16x16x32_bf16(af1, bf0, acc[1][0], 0, 0, 0);
            acc[1][1] = __builtin_amdgcn_mfma_f32_16x16x32_bf16(af1, bf1, acc[1][1], 0, 0, 0);
        }
        // ---------- odd sub-step: set1 -> buffer 1 ----------
        As[1][srow * 9 + sc] = pa0_1;
        As[1][srow * 9 + sc + 1] = pa1_1;
        Bs[1][srow * 9 + sc] = pb0_1;
        Bs[1][srow * 9 + sc + 1] = pb1_1;
        if (k0 + 192 < NK) {
            pa0_1 = *(const int4*)(Ab + k0 + 192);
            pa1_1 = *(const int4*)(Ab + k0 + 200);
            pb0_1 = *(const int4*)(Bb + k0 + 192);
            pb1_1 = *(const int4*)(Bb + k0 + 200);
        }
        __syncthreads();
        #pragma unroll
        for (int kk = 0; kk < 2; ++kk) {
            const int kc = kk * 4 + (l >> 4);
            bf16x8 af0 = *(const bf16x8*)&As[1][(wm + (l & 15)) * 9 + kc];
            bf16x8 af1 = *(const bf16x8*)&As[1][(wm + 16 + (l & 15)) * 9 + kc];
            bf16x8 bf0 = *(const bf16x8*)&Bs[1][(wn + (l & 15)) * 9 + kc];
            bf16x8 bf1 = *(const bf16x8*)&Bs[1][(wn + 16 + (l & 15)) * 9 + kc];
            acc[0][0] = __builtin_amdgcn_mfma_f32_16x16x32_bf16(af0, bf0, acc[0][0], 0, 0, 0);
            acc[0][1] = __builtin_amdgcn_mfma_f32_16x16x32_bf16(af0, bf1, acc[0][1], 0, 0, 0);
            acc[1][0] = __builtin_amdgcn_mfma_f32_16x16x32_bf16(af1, bf0, acc[1][0], 0, 0, 0);
            acc[1][1] = __builtin_amdgcn_mfma_f32_16x16x32_bf16(af1, bf1, acc[1][1], 0, 0, 0);
        }
    }

    // epilogue: bias + ELU + store + column stats
    const int r0 = m0 + wm + ((l >> 4) << 2);
    #pragma unroll
    for (int ni = 0; ni < 2; ++ni) {
        const int col = n0 + wn + ni * 16 + (l & 15);
        const float bias = b1[col];
        float s1 = 0.f, s2 = 0.f;
        #pragma unroll
        for (int mi = 0; mi < 2; ++mi) {
            #pragma unroll
            for (int rr = 0; rr < 4; ++rr) {
                float v = acc[mi][ni][rr] + bias;
                v = v > 0.f ? v : expm1f(v);
                h[(long)(r0 + mi * 16 + rr) * NE + col] = v;
                s1 += v; s2 += v * v;
            }
        }
        // lanes l, l^16, l^32, l^48 share col; reduce 32 rows of this wave
        s1 += __shfl_xor(s1, 16); s2 += __shfl_xor(s2, 16);
        s1 += __shfl_xor(s1, 32); s2 += __shfl_xor(s2, 32);
        if (l < 16) {
            unsafeAtomicAdd(&s1s2[col], s1);
            unsafeAtomicAdd(&s1s2[NE + col], s2);
        }
    }
}

// ---------------------------------------------------------------------------
// Kernel 3: fused finalize + output. Each block recomputes the folded BN/W2
// coefficients (4 KB read, L2-hot) then does 4 rows of the 512-dot product.
// ---------------------------------------------------------------------------
__global__ __launch_bounds__(256) void out_kernel(
    const float* __restrict__ h, const float* __restrict__ s1s2,
    const float* __restrict__ gamma, const float* __restrict__ beta,
    const float* __restrict__ W2, const float* __restrict__ b2,
    float* __restrict__ out)
{
    __shared__ float coef[NE];
    __shared__ float red[256];
    const int t = threadIdx.x;

    float term = 0.f;
    #pragma unroll
    for (int i = 0; i < 2; ++i) {
        const int e = t + i * 256;
        const float s1 = s1s2[e];
        const float s2 = s1s2[NE + e];
        const float mu = s1 * (1.0f / NB);
        const float var = s2 * (1.0f / NB) - mu * mu;
        const float rs = rsqrtf(var + 1e-5f);
        const float g = gamma[e], wv = W2[e];
        coef[e] = rs * g * wv;
        term += (beta[e] - mu * rs * g) * wv;
    }
    red[t] = term;
    __syncthreads();
    #pragma unroll
    for (int off = 128; off > 0; off >>= 1) {
        if (t < off) red[t] += red[t + off];
        __syncthreads();
    }
    const float cst = red[0] + b2[0];

    const int w = t >> 6;
    const int l = t & 63;
    const int row = blockIdx.x * 4 + w;
    const f32x4* h4 = (const f32x4*)(h + (long)row * NE);
    f32x4 x0 = h4[l * 2], x1 = h4[l * 2 + 1];
    f32x4 c0 = *(const f32x4*)&coef[l * 8];
    f32x4 c1 = *(const f32x4*)&coef[l * 8 + 4];
    float dot = x0.x * c0.x + x0.y * c0.y + x0.z * c0.z + x0.w * c0.w
              + x1.x * c1.x + x1.y * c1.y + x1.z * c1.z + x1.w * c1.w;
    #pragma unroll
    for (int off = 32; off > 0; off >>= 1) dot += __shfl_down(dot, off);
    if (l == 0) out[row] = dot + cst;
}

// ---------------------------------------------------------------------------
extern "C" void kernel_launch(void* const* d_in, const int* in_sizes, int n_in,
                              void* d_out, int out_size, void* d_ws, size_t ws_size,
                              hipStream_t stream)
{
    const float* q    = (const float*)d_in[0];
    const float* vq   = (const float*)d_in[1];
    const float* aa   = (const float*)d_in[2];
    const float* va   = (const float*)d_in[3];
    const float* W1   = (const float*)d_in[4];
    const float* b1   = (const float*)d_in[5];
    const float* gam  = (const float*)d_in[6];
    const float* bet  = (const float*)d_in[7];
    const float* W2   = (const float*)d_in[8];
    const float* b2   = (const float*)d_in[9];
    const int* qlen   = (const int*)d_in[10];
    const int* alen   = (const int*)d_in[11];
    float* out = (float*)d_out;

    char* ws = (char*)d_ws;
    unsigned short* feat = (unsigned short*)ws;                 // 20,971,520 B
    unsigned short* w1t  = (unsigned short*)(ws + 20971520);    //  5,242,880 B
    float* hbuf          = (float*)(ws + 26214400);             //  4,194,304 B
    float* s1s2          = (float*)(ws + 30408704);             //      4,096 B

    reduce_w1t_kernel<<<7680, 256, 0, stream>>>(
        (const f32x4*)q, (const f32x4*)vq, (const f32x4*)aa, (const f32x4*)va,
        qlen, alen, (ushort4*)feat, W1, w1t, s1s2);

    gemm_kernel<<<256, 256, 0, stream>>>(feat, w1t, b1, hbuf, s1s2);

    out_kernel<<<512, 256, 0, stream>>>(hbuf, s1s2, gam, bet, W2, b2, out);
}

// Round 9
// 337.749 us; speedup vs baseline: 1.5542x; 1.5542x over previous
//
#include <hip/hip_runtime.h>
#include <hip/hip_bf16.h>

typedef __attribute__((ext_vector_type(8))) short bf16x8;
typedef __attribute__((ext_vector_type(4))) float f32x4;

#define NB 2048      // batch
#define ND 1280      // per-stream dim
#define NK 5120      // 4*ND
#define NE 512       // EMBED

static __device__ inline unsigned short f2bf(float x) {
    union { float f; unsigned u; } c; c.f = x;
    unsigned r = c.u + 0x7FFFu + ((c.u >> 16) & 1u);
    return (unsigned short)(r >> 16);
}

// ---------------------------------------------------------------------------
// Kernel 1: fused masked-mean over T -> feat bf16 [B][4D].
// Wave-per-row layout: block = 4 consecutive b-rows (one per wave); lane l
// owns float4-chunks l+64j (j=0..4) of its row -> every load instruction is
// 1 KB contiguous, block window is one 20 KB contiguous span per t-plane,
// len is wave-uniform (no masked-loop divergence).
// blocks [0,2048): reduce (segs ordered 1,3,0,2 for tail-packing).
// blocks [2048,4608): W1 transpose->bf16 (+zero s1s2).
// ---------------------------------------------------------------------------
__global__ __launch_bounds__(256) void reduce_w1t_kernel(
    const f32x4* __restrict__ q, const f32x4* __restrict__ vq,
    const f32x4* __restrict__ aa, const f32x4* __restrict__ va,
    const int* __restrict__ qlen, const int* __restrict__ alen,
    ushort4* __restrict__ feat,
    const float* __restrict__ W1, unsigned short* __restrict__ w1t,
    float* __restrict__ s1s2)
{
    __shared__ unsigned short lds[32][33];

    if (blockIdx.x >= 2048) {
        // ---- W1 transpose path ----
        const int bid = blockIdx.x - 2048;
        if (bid == 0) {
            ((f32x4*)s1s2)[threadIdx.x] = (f32x4){0.f, 0.f, 0.f, 0.f};
        }
        const int kb = (bid >> 4) * 32;
        const int nb = (bid & 15) * 32;
        const int tx = threadIdx.x & 31;
        const int ty = threadIdx.x >> 5;   // 0..7
        #pragma unroll
        for (int i = 0; i < 4; ++i) {
            int k = kb + ty + i * 8;
            lds[ty + i * 8][tx] = f2bf(W1[(long)k * NE + nb + tx]);
        }
        __syncthreads();
        #pragma unroll
        for (int i = 0; i < 4; ++i) {
            int n = nb + ty + i * 8;
            w1t[(long)n * NK + kb + tx] = lds[tx][ty + i * 8];
        }
        return;
    }

    // ---- masked-mean path (seg order: 1,3,0,2) ----
    const int blk = blockIdx.x;
    const int sb = blk >> 9;                    // 0..3
    const int seg = (sb == 0) ? 1 : (sb == 1) ? 3 : (sb == 2) ? 0 : 2;
    const int rb = blk & 511;
    const int wv = threadIdx.x >> 6;            // 0..3 -> row within block
    const int lane = threadIdx.x & 63;
    const int b = rb * 4 + wv;

    const long rowbase = (long)b * 320 + lane;  // float4 units
    const long stride = (long)NB * 320;         // one t-plane

    f32x4 a0 = {0.f,0.f,0.f,0.f}, a1 = {0.f,0.f,0.f,0.f}, a2 = {0.f,0.f,0.f,0.f},
          a3 = {0.f,0.f,0.f,0.f}, a4 = {0.f,0.f,0.f,0.f};
    float inv;

    if (seg == 1 || seg == 3) {
        const f32x4* src = (seg == 1) ? vq : va;
        #pragma unroll 4
        for (int t = 0; t < 64; ++t) {
            const f32x4* p = src + rowbase + (long)t * stride;
            a0 += __builtin_nontemporal_load(&p[0]);
            a1 += __builtin_nontemporal_load(&p[64]);
            a2 += __builtin_nontemporal_load(&p[128]);
            a3 += __builtin_nontemporal_load(&p[192]);
            a4 += __builtin_nontemporal_load(&p[256]);
        }
        inv = 1.0f / 64.0f;
    } else {
        const f32x4* src = (seg == 0) ? q : aa;
        const int len = (seg == 0) ? qlen[b] : alen[b];   // wave-uniform
        #pragma unroll 2
        for (int t = 0; t < len; ++t) {
            const f32x4* p = src + rowbase + (long)t * stride;
            a0 += __builtin_nontemporal_load(&p[0]);
            a1 += __builtin_nontemporal_load(&p[64]);
            a2 += __builtin_nontemporal_load(&p[128]);
            a3 += __builtin_nontemporal_load(&p[192]);
            a4 += __builtin_nontemporal_load(&p[256]);
        }
        inv = 1.0f / (float)len;
    }

    const long fb = (long)b * (NK / 4) + seg * 320 + lane;
    ushort4 o;
    o.x = f2bf(a0.x * inv); o.y = f2bf(a0.y * inv);
    o.z = f2bf(a0.z * inv); o.w = f2bf(a0.w * inv);
    feat[fb] = o;
    o.x = f2bf(a1.x * inv); o.y = f2bf(a1.y * inv);
    o.z = f2bf(a1.z * inv); o.w = f2bf(a1.w * inv);
    feat[fb + 64] = o;
    o.x = f2bf(a2.x * inv); o.y = f2bf(a2.y * inv);
    o.z = f2bf(a2.z * inv); o.w = f2bf(a2.w * inv);
    feat[fb + 128] = o;
    o.x = f2bf(a3.x * inv); o.y = f2bf(a3.y * inv);
    o.z = f2bf(a3.z * inv); o.w = f2bf(a3.w * inv);
    feat[fb + 192] = o;
    o.x = f2bf(a4.x * inv); o.y = f2bf(a4.y * inv);
    o.z = f2bf(a4.z * inv); o.w = f2bf(a4.w * inv);
    feat[fb + 256] = o;
}

// ---------------------------------------------------------------------------
// Kernel 2: bf16 MFMA GEMM, tiles 64x64, wave=32x32 (acc[2][2]), K=5120,
// grid 256 blocks (1/CU), XCD-aware mapping (m = bid&31).
// LDS double-buffer + prefetch depth 2 (two named reg sets, statically
// unrolled x2); one barrier per sub-step. Fused bias/ELU/store/BN epilogue.
// ---------------------------------------------------------------------------
__global__ __launch_bounds__(256) void gemm_kernel(
    const unsigned short* __restrict__ feat, const unsigned short* __restrict__ w1t,
    const float* __restrict__ b1,
    float* __restrict__ h, float* __restrict__ s1s2)
{
    __shared__ int4 As[2][64 * 9];   // 2 x 64 rows x 144B (16B pad)
    __shared__ int4 Bs[2][64 * 9];

    const int bid = blockIdx.x;
    const int m0 = (bid & 31) << 6;         // m-tile fastest -> same-m on same XCD
    const int n0 = (bid >> 5) << 6;         // 0..448

    const int t = threadIdx.x;
    const int l = t & 63;
    const int w = t >> 6;
    const int wm = (w >> 1) << 5;           // 0 or 32
    const int wn = (w & 1) << 5;            // 0 or 32
    const int srow = t >> 2;                // 0..63
    const int sc = (t & 3) << 1;            // 16B-chunk 0,2,4,6

    const unsigned short* Ab = feat + (long)(m0 + srow) * NK + sc * 8;
    const unsigned short* Bb = w1t + (long)(n0 + srow) * NK + sc * 8;

    f32x4 acc[2][2] = {};

    // prefetch set 0 (k-step k0) and set 1 (k-step k0+64)
    int4 pa0_0 = *(const int4*)(Ab);
    int4 pa1_0 = *(const int4*)(Ab + 8);
    int4 pb0_0 = *(const int4*)(Bb);
    int4 pb1_0 = *(const int4*)(Bb + 8);
    int4 pa0_1 = *(const int4*)(Ab + 64);
    int4 pa1_1 = *(const int4*)(Ab + 72);
    int4 pb0_1 = *(const int4*)(Bb + 64);
    int4 pb1_1 = *(const int4*)(Bb + 72);

    #pragma unroll 1
    for (int k0 = 0; k0 < NK; k0 += 128) {
        // ---------- even sub-step: set0 -> buffer 0 ----------
        As[0][srow * 9 + sc] = pa0_0;
        As[0][srow * 9 + sc + 1] = pa1_0;
        Bs[0][srow * 9 + sc] = pb0_0;
        Bs[0][srow * 9 + sc + 1] = pb1_0;
        if (k0 + 128 < NK) {
            pa0_0 = *(const int4*)(Ab + k0 + 128);
            pa1_0 = *(const int4*)(Ab + k0 + 136);
            pb0_0 = *(const int4*)(Bb + k0 + 128);
            pb1_0 = *(const int4*)(Bb + k0 + 136);
        }
        __syncthreads();
        #pragma unroll
        for (int kk = 0; kk < 2; ++kk) {
            const int kc = kk * 4 + (l >> 4);
            bf16x8 af0 = *(const bf16x8*)&As[0][(wm + (l & 15)) * 9 + kc];
            bf16x8 af1 = *(const bf16x8*)&As[0][(wm + 16 + (l & 15)) * 9 + kc];
            bf16x8 bf0 = *(const bf16x8*)&Bs[0][(wn + (l & 15)) * 9 + kc];
            bf16x8 bf1 = *(const bf16x8*)&Bs[0][(wn + 16 + (l & 15)) * 9 + kc];
            acc[0][0] = __builtin_amdgcn_mfma_f32_16x16x32_bf16(af0, bf0, acc[0][0], 0, 0, 0);
            acc[0][1] = __builtin_amdgcn_mfma_f32_16x16x32_bf16(af0, bf1, acc[0][1], 0, 0, 0);
            acc[1][0] = __builtin_amdgcn_mfma_f32_16x16x32_bf16(af1, bf0, acc[1][0], 0, 0, 0);
            acc[1][1] = __builtin_amdgcn_mfma_f32_16x16x32_bf16(af1, bf1, acc[1][1], 0, 0, 0);
        }
        // ---------- odd sub-step: set1 -> buffer 1 ----------
        As[1][srow * 9 + sc] = pa0_1;
        As[1][srow * 9 + sc + 1] = pa1_1;
        Bs[1][srow * 9 + sc] = pb0_1;
        Bs[1][srow * 9 + sc + 1] = pb1_1;
        if (k0 + 192 < NK) {
            pa0_1 = *(const int4*)(Ab + k0 + 192);
            pa1_1 = *(const int4*)(Ab + k0 + 200);
            pb0_1 = *(const int4*)(Bb + k0 + 192);
            pb1_1 = *(const int4*)(Bb + k0 + 200);
        }
        __syncthreads();
        #pragma unroll
        for (int kk = 0; kk < 2; ++kk) {
            const int kc = kk * 4 + (l >> 4);
            bf16x8 af0 = *(const bf16x8*)&As[1][(wm + (l & 15)) * 9 + kc];
            bf16x8 af1 = *(const bf16x8*)&As[1][(wm + 16 + (l & 15)) * 9 + kc];
            bf16x8 bf0 = *(const bf16x8*)&Bs[1][(wn + (l & 15)) * 9 + kc];
            bf16x8 bf1 = *(const bf16x8*)&Bs[1][(wn + 16 + (l & 15)) * 9 + kc];
            acc[0][0] = __builtin_amdgcn_mfma_f32_16x16x32_bf16(af0, bf0, acc[0][0], 0, 0, 0);
            acc[0][1] = __builtin_amdgcn_mfma_f32_16x16x32_bf16(af0, bf1, acc[0][1], 0, 0, 0);
            acc[1][0] = __builtin_amdgcn_mfma_f32_16x16x32_bf16(af1, bf0, acc[1][0], 0, 0, 0);
            acc[1][1] = __builtin_amdgcn_mfma_f32_16x16x32_bf16(af1, bf1, acc[1][1], 0, 0, 0);
        }
    }

    // epilogue: bias + ELU + store + column stats
    const int r0 = m0 + wm + ((l >> 4) << 2);
    #pragma unroll
    for (int ni = 0; ni < 2; ++ni) {
        const int col = n0 + wn + ni * 16 + (l & 15);
        const float bias = b1[col];
        float s1 = 0.f, s2 = 0.f;
        #pragma unroll
        for (int mi = 0; mi < 2; ++mi) {
            #pragma unroll
            for (int rr = 0; rr < 4; ++rr) {
                float v = acc[mi][ni][rr] + bias;
                v = v > 0.f ? v : expm1f(v);
                h[(long)(r0 + mi * 16 + rr) * NE + col] = v;
                s1 += v; s2 += v * v;
            }
        }
        // lanes l, l^16, l^32, l^48 share col; reduce 32 rows of this wave
        s1 += __shfl_xor(s1, 16); s2 += __shfl_xor(s2, 16);
        s1 += __shfl_xor(s1, 32); s2 += __shfl_xor(s2, 32);
        if (l < 16) {
            unsafeAtomicAdd(&s1s2[col], s1);
            unsafeAtomicAdd(&s1s2[NE + col], s2);
        }
    }
}

// ---------------------------------------------------------------------------
// Kernel 3: fused finalize + output. Each block recomputes the folded BN/W2
// coefficients (4 KB read, L2-hot) then does 4 rows of the 512-dot product.
// ---------------------------------------------------------------------------
__global__ __launch_bounds__(256) void out_kernel(
    const float* __restrict__ h, const float* __restrict__ s1s2,
    const float* __restrict__ gamma, const float* __restrict__ beta,
    const float* __restrict__ W2, const float* __restrict__ b2,
    float* __restrict__ out)
{
    __shared__ float coef[NE];
    __shared__ float red[256];
    const int t = threadIdx.x;

    float term = 0.f;
    #pragma unroll
    for (int i = 0; i < 2; ++i) {
        const int e = t + i * 256;
        const float s1 = s1s2[e];
        const float s2 = s1s2[NE + e];
        const float mu = s1 * (1.0f / NB);
        const float var = s2 * (1.0f / NB) - mu * mu;
        const float rs = rsqrtf(var + 1e-5f);
        const float g = gamma[e], wv = W2[e];
        coef[e] = rs * g * wv;
        term += (beta[e] - mu * rs * g) * wv;
    }
    red[t] = term;
    __syncthreads();
    #pragma unroll
    for (int off = 128; off > 0; off >>= 1) {
        if (t < off) red[t] += red[t + off];
        __syncthreads();
    }
    const float cst = red[0] + b2[0];

    const int w = t >> 6;
    const int l = t & 63;
    const int row = blockIdx.x * 4 + w;
    const f32x4* h4 = (const f32x4*)(h + (long)row * NE);
    f32x4 x0 = h4[l * 2], x1 = h4[l * 2 + 1];
    f32x4 c0 = *(const f32x4*)&coef[l * 8];
    f32x4 c1 = *(const f32x4*)&coef[l * 8 + 4];
    float dot = x0.x * c0.x + x0.y * c0.y + x0.z * c0.z + x0.w * c0.w
              + x1.x * c1.x + x1.y * c1.y + x1.z * c1.z + x1.w * c1.w;
    #pragma unroll
    for (int off = 32; off > 0; off >>= 1) dot += __shfl_down(dot, off);
    if (l == 0) out[row] = dot + cst;
}

// ---------------------------------------------------------------------------
extern "C" void kernel_launch(void* const* d_in, const int* in_sizes, int n_in,
                              void* d_out, int out_size, void* d_ws, size_t ws_size,
                              hipStream_t stream)
{
    const float* q    = (const float*)d_in[0];
    const float* vq   = (const float*)d_in[1];
    const float* aa   = (const float*)d_in[2];
    const float* va   = (const float*)d_in[3];
    const float* W1   = (const float*)d_in[4];
    const float* b1   = (const float*)d_in[5];
    const float* gam  = (const float*)d_in[6];
    const float* bet  = (const float*)d_in[7];
    const float* W2   = (const float*)d_in[8];
    const float* b2   = (const float*)d_in[9];
    const int* qlen   = (const int*)d_in[10];
    const int* alen   = (const int*)d_in[11];
    float* out = (float*)d_out;

    char* ws = (char*)d_ws;
    unsigned short* feat = (unsigned short*)ws;                 // 20,971,520 B
    unsigned short* w1t  = (unsigned short*)(ws + 20971520);    //  5,242,880 B
    float* hbuf          = (float*)(ws + 26214400);             //  4,194,304 B
    float* s1s2          = (float*)(ws + 30408704);             //      4,096 B

    reduce_w1t_kernel<<<4608, 256, 0, stream>>>(
        (const f32x4*)q, (const f32x4*)vq, (const f32x4*)aa, (const f32x4*)va,
        qlen, alen, (ushort4*)feat, W1, w1t, s1s2);

    gemm_kernel<<<256, 256, 0, stream>>>(feat, w1t, b1, hbuf, s1s2);

    out_kernel<<<512, 256, 0, stream>>>(hbuf, s1s2, gam, bet, W2, b2, out);
}